// Round 1
// baseline (945.734 us; speedup 1.0000x reference)
//
#include <hip/hip_runtime.h>
#include <hip/hip_bf16.h>

#define N_ROWS 4096
#define H_DIM  512
#define V_DIM  50257
#define BM 128
#define BN 128
#define BK 32
#define VT_TOTAL 393            // ceil(V/BN)
#define V_PAD (VT_TOTAL * BN)   // 50304
#define NCHUNK 64
#define NPART (NCHUNK * 2)      // partials per row (chunk x wn)
#define LOG2E 1.4426950408889634f

typedef __attribute__((ext_vector_type(8))) short short8;
typedef __attribute__((ext_vector_type(4))) float f32x4;

static __device__ __forceinline__ unsigned short f2bf(float f) {
  unsigned u = __float_as_uint(f);
  u = (u + 0x7fffu + ((u >> 16) & 1u)) >> 16;   // RNE
  return (unsigned short)u;
}

static __device__ __forceinline__ void gload_lds16(const void* g, void* l) {
  __builtin_amdgcn_global_load_lds(
      (const __attribute__((address_space(1))) void*)g,
      (__attribute__((address_space(3))) void*)l, 16, 0, 0);
}

// ---------------- kernel A: fp32 -> bf16 conversion (W padded to V_PAD) ----
__global__ void convert_kernel(const float* __restrict__ X,
                               const float* __restrict__ W,
                               __hip_bfloat16* __restrict__ Xb,
                               __hip_bfloat16* __restrict__ Wb) {
  const long wtot8 = (long)V_PAD * H_DIM / 8;   // 3,219,456
  const long xtot8 = (long)N_ROWS * H_DIM / 8;  //   262,144
  long i = (long)blockIdx.x * blockDim.x + threadIdx.x;
  unsigned short o[8];
  if (i < wtot8) {
    long base = i * 8;
    long row = base >> 9;   // /512
    if (row < V_DIM) {
      const float4* s = (const float4*)(W + base);
      float4 a = s[0], b = s[1];
      o[0]=f2bf(a.x); o[1]=f2bf(a.y); o[2]=f2bf(a.z); o[3]=f2bf(a.w);
      o[4]=f2bf(b.x); o[5]=f2bf(b.y); o[6]=f2bf(b.z); o[7]=f2bf(b.w);
    } else {
      #pragma unroll
      for (int k = 0; k < 8; ++k) o[k] = 0;
    }
    *(short8*)(Wb + base) = *(const short8*)o;
  } else if (i < wtot8 + xtot8) {
    long base = (i - wtot8) * 8;
    const float4* s = (const float4*)(X + base);
    float4 a = s[0], b = s[1];
    o[0]=f2bf(a.x); o[1]=f2bf(a.y); o[2]=f2bf(a.z); o[3]=f2bf(a.w);
    o[4]=f2bf(b.x); o[5]=f2bf(b.y); o[6]=f2bf(b.z); o[7]=f2bf(b.w);
    *(short8*)(Xb + base) = *(const short8*)o;
  }
}

// ---------------- kernel B: fused GEMM + online softmax stats -------------
// Grid (32, NCHUNK). Block 256 = 4 waves (2x2 over the 128x128 tile).
// Per (row, chunk, wn): partial {m_l, s_l, m_t, s_t, d} in natural-log space.
__global__ __launch_bounds__(256, 2)
void fused_kernel(const __hip_bfloat16* __restrict__ Xb,
                  const __hip_bfloat16* __restrict__ Wb,
                  const float* __restrict__ bias,
                  const float* __restrict__ targets,
                  float* __restrict__ partials) {
  __shared__ __hip_bfloat16 As[BM * BK];
  __shared__ __hip_bfloat16 Bs[BN * BK];

  const int tid  = threadIdx.x;
  const int lane = tid & 63;
  const int wid  = tid >> 6;
  const int wm   = wid >> 1;
  const int wn   = wid & 1;
  const int q    = lane >> 4;
  const int c15  = lane & 15;
  const int brow = blockIdx.x;
  const int chunk = blockIdx.y;

  float ml[16], sl[16], mt[16], st[16], dd[16];
  #pragma unroll
  for (int i = 0; i < 16; ++i) {
    ml[i] = -1e30f; sl[i] = 0.f; mt[i] = -1e30f; st[i] = 0.f; dd[i] = 0.f;
  }

  // staging: thread t covers LDS bytes [t*16, t*16+16) of an 8 KB tile;
  // row = t/4 (0..63), k-start = (t&3)*8; second call covers rows 64..127.
  const int srow = tid >> 2;
  const int sk   = (tid & 3) * 8;
  const long abase = (long)(brow * BM + srow) * H_DIM + sk;
  char* AsB = (char*)As;
  char* BsB = (char*)Bs;

  for (int vt = chunk; vt < VT_TOTAL; vt += NCHUNK) {
    const int vbase = vt * BN;
    const int cb = vbase + wn * 64;

    f32x4 acc[4][4];
    #pragma unroll
    for (int m = 0; m < 4; ++m)
      #pragma unroll
      for (int n = 0; n < 4; ++n)
        acc[m][n] = (f32x4){0.f, 0.f, 0.f, 0.f};

    const long bbase = (long)(vbase + srow) * H_DIM + sk;

    for (int kk = 0; kk < H_DIM; kk += BK) {
      gload_lds16(Xb + abase + kk,                    AsB + wid * 1024);
      gload_lds16(Xb + abase + 64 * H_DIM + kk,       AsB + 4096 + wid * 1024);
      gload_lds16(Wb + bbase + kk,                    BsB + wid * 1024);
      gload_lds16(Wb + bbase + 64 * H_DIM + kk,       BsB + 4096 + wid * 1024);
      __syncthreads();
      short8 af[4], bf[4];
      #pragma unroll
      for (int m = 0; m < 4; ++m)
        af[m] = *(const short8*)&As[(wm * 64 + m * 16 + c15) * BK + q * 8];
      #pragma unroll
      for (int n = 0; n < 4; ++n)
        bf[n] = *(const short8*)&Bs[(wn * 64 + n * 16 + c15) * BK + q * 8];
      #pragma unroll
      for (int m = 0; m < 4; ++m)
        #pragma unroll
        for (int n = 0; n < 4; ++n)
          acc[m][n] = __builtin_amdgcn_mfma_f32_16x16x32_bf16(af[m], bf[n], acc[m][n], 0, 0, 0);
      __syncthreads();
    }

    // epilogue: bias add + targets stream + online stats update
    float bv[4];
    bool valn[4];
    #pragma unroll
    for (int n = 0; n < 4; ++n) {
      int col = cb + n * 16 + c15;
      valn[n] = (col < V_DIM);
      bv[n] = valn[n] ? bias[col] : 0.f;
    }
    const long tcb = (long)cb + c15;
    #pragma unroll
    for (int m = 0; m < 4; ++m) {
      const int rloc = wm * 64 + m * 16 + q * 4;
      const long rg0 = (long)(brow * BM + rloc);
      #pragma unroll
      for (int j = 0; j < 4; ++j) {
        const float* trow = targets + (rg0 + j) * (long)V_DIM;
        float L[4], T[4];
        #pragma unroll
        for (int n = 0; n < 4; ++n) {
          L[n] = acc[m][n][j] + bv[n];
          T[n] = valn[n] ? trow[tcb + n * 16] : -1e30f;
        }
        const int i = m * 4 + j;
        // --- logits lse (online) ---
        float tmax = -1e30f;
        #pragma unroll
        for (int n = 0; n < 4; ++n) tmax = fmaxf(tmax, valn[n] ? L[n] : -1e30f);
        float nm = fmaxf(ml[i], tmax);
        float ssum = 0.f;
        #pragma unroll
        for (int n = 0; n < 4; ++n)
          ssum += valn[n] ? exp2f((L[n] - nm) * LOG2E) : 0.f;
        sl[i] = sl[i] * exp2f((ml[i] - nm) * LOG2E) + ssum;
        ml[i] = nm;
        // --- target softmax num/denom (online) ---
        float tmx = fmaxf(fmaxf(T[0], T[1]), fmaxf(T[2], T[3]));
        float nmt = fmaxf(mt[i], tmx);
        float sc = exp2f((mt[i] - nmt) * LOG2E);
        float stsum = 0.f, dsum = 0.f;
        #pragma unroll
        for (int n = 0; n < 4; ++n) {
          float e = valn[n] ? exp2f((T[n] - nmt) * LOG2E) : 0.f;
          stsum += e;
          dsum += e * (valn[n] ? L[n] : 0.f);
        }
        st[i] = st[i] * sc + stsum;
        dd[i] = dd[i] * sc + dsum;
        mt[i] = nmt;
      }
    }
  }

  // butterfly-merge the 16 lanes (c15 bits) of each q-group
  #pragma unroll
  for (int off = 1; off <= 8; off <<= 1) {
    #pragma unroll
    for (int i = 0; i < 16; ++i) {
      float ml2 = __shfl_xor(ml[i], off);
      float sl2 = __shfl_xor(sl[i], off);
      float mt2 = __shfl_xor(mt[i], off);
      float st2 = __shfl_xor(st[i], off);
      float dd2 = __shfl_xor(dd[i], off);
      float nm = fmaxf(ml[i], ml2);
      sl[i] = sl[i] * exp2f((ml[i] - nm) * LOG2E) + sl2 * exp2f((ml2 - nm) * LOG2E);
      ml[i] = nm;
      float nmt = fmaxf(mt[i], mt2);
      float e1 = exp2f((mt[i] - nmt) * LOG2E);
      float e2 = exp2f((mt2 - nmt) * LOG2E);
      st[i] = st[i] * e1 + st2 * e2;
      dd[i] = dd[i] * e1 + dd2 * e2;
      mt[i] = nmt;
    }
  }
  if (c15 == 0) {
    #pragma unroll
    for (int m = 0; m < 4; ++m)
      #pragma unroll
      for (int j = 0; j < 4; ++j) {
        int i = m * 4 + j;
        long r = (long)(brow * BM + wm * 64 + m * 16 + q * 4 + j);
        float* p = partials + (r * NPART + chunk * 2 + wn) * 5;
        p[0] = ml[i]; p[1] = sl[i]; p[2] = mt[i]; p[3] = st[i]; p[4] = dd[i];
      }
  }
}

// ---------------- kernel C: merge partials -> per-row loss ----------------
__global__ void rowloss_kernel(const float* __restrict__ partials,
                               float* __restrict__ rowloss) {
  int r = blockIdx.x * blockDim.x + threadIdx.x;
  if (r >= N_ROWS) return;
  const float* p = partials + (long)r * NPART * 5;
  float ml = -1e30f, sl = 0.f, mt = -1e30f, st = 0.f, dd = 0.f;
  for (int c = 0; c < NPART; ++c) {
    float ml2 = p[0], sl2 = p[1], mt2 = p[2], st2 = p[3], dd2 = p[4];
    p += 5;
    float nm = fmaxf(ml, ml2);
    sl = sl * exp2f((ml - nm) * LOG2E) + sl2 * exp2f((ml2 - nm) * LOG2E);
    ml = nm;
    float nmt = fmaxf(mt, mt2);
    float e1 = exp2f((mt - nmt) * LOG2E);
    float e2 = exp2f((mt2 - nmt) * LOG2E);
    st = st * e1 + st2 * e2;
    dd = dd * e1 + dd2 * e2;
    mt = nmt;
  }
  float lse = ml + logf(sl);
  rowloss[r] = lse - dd / st;
}

// ---------------- kernel D: final scalar reduce ---------------------------
__global__ void final_kernel(const float* __restrict__ rowloss,
                             float* __restrict__ out) {
  __shared__ float sm[4];
  float s = 0.f;
  for (int i = threadIdx.x; i < N_ROWS; i += 256) s += rowloss[i];
  #pragma unroll
  for (int off = 32; off > 0; off >>= 1) s += __shfl_down(s, off);
  if ((threadIdx.x & 63) == 0) sm[threadIdx.x >> 6] = s;
  __syncthreads();
  if (threadIdx.x == 0) out[0] = (sm[0] + sm[1] + sm[2] + sm[3]) * (1.0f / (float)N_ROWS);
}

extern "C" void kernel_launch(void* const* d_in, const int* in_sizes, int n_in,
                              void* d_out, int out_size, void* d_ws, size_t ws_size,
                              hipStream_t stream) {
  const float* x       = (const float*)d_in[0];   // [4096, 512]
  const float* targets = (const float*)d_in[1];   // [4096, 50257]
  const float* weight  = (const float*)d_in[2];   // [50257, 512]
  const float* bias    = (const float*)d_in[3];   // [50257]
  float* out = (float*)d_out;

  char* ws = (char*)d_ws;
  __hip_bfloat16* Wb = (__hip_bfloat16*)ws;                     // 51,511,296 B
  size_t off = (size_t)V_PAD * H_DIM * 2;
  __hip_bfloat16* Xb = (__hip_bfloat16*)(ws + off);             //  4,194,304 B
  off += (size_t)N_ROWS * H_DIM * 2;
  float* partials = (float*)(ws + off);                         // 10,485,760 B
  off += (size_t)N_ROWS * NPART * 5 * sizeof(float);
  float* rowloss = (float*)(ws + off);                          //     16,384 B

  convert_kernel<<<13600, 256, 0, stream>>>(x, weight, Xb, Wb);
  dim3 grid(N_ROWS / BM, NCHUNK);
  fused_kernel<<<grid, 256, 0, stream>>>(Xb, Wb, bias, targets, partials);
  rowloss_kernel<<<N_ROWS / 256, 256, 0, stream>>>(partials, rowloss);
  final_kernel<<<1, 256, 0, stream>>>(rowloss, out);
}